// Round 8
// baseline (257.974 us; speedup 1.0000x reference)
//
#include <hip/hip_runtime.h>

#define BB 8
#define CC 64
#define HH 128
#define WW 128
#define TT 3
#define LL 4
#define MM 3

#define PW 130                         // padded spatial dim
#define CHP ((size_t)PW * PW * 16)     // halves per 16-ch chunk plane
#define IMGH ((size_t)PW * PW * CC)    // halves per padded image (= 4*CHP)

typedef _Float16 half8 __attribute__((ext_vector_type(8)));
typedef _Float16 half4 __attribute__((ext_vector_type(4)));
typedef float floatx16 __attribute__((ext_vector_type(16)));

__device__ __forceinline__ void async_ld16(const _Float16* g, _Float16* l) {
    __builtin_amdgcn_global_load_lds(
        (const __attribute__((address_space(1))) void*)g,
        (__attribute__((address_space(3))) void*)l, 16, 0, 0);
}

// ---------------------------------------------------------------------------
// Weight prep (+ inline routing): every block recomputes the argmax chain,
// gathers the selected module, fp32 -> fp16, A-frag order:
// W3[tl][tap][c(2)][il(2)][o(2)][lane(64)*8] -- one a-frag = contiguous 1 KB.
// ---------------------------------------------------------------------------
__global__ __launch_bounds__(256) void prep_weights(
    const float* __restrict__ enc_w, // [L][M][64][64][3][3]
    const float* __restrict__ alpha0,
    const float* __restrict__ alphas,
    const float* __restrict__ g0,
    const float* __restrict__ gs,
    int* __restrict__ sel,           // [T][L]
    _Float16* __restrict__ W3)       // [12][36864]
{
    int tl = blockIdx.y;
    int t = tl >> 2, layer = tl & 3;
    int idx = 0;
    for (int l = 0; l <= layer; ++l) {
        const float *a, *g;
        if (l == 0) { a = alpha0 + t * MM; g = g0 + t * MM; }
        else {
            int off = (((l - 1) * TT + t) * MM + idx) * MM;
            a = alphas + off; g = gs + off;
        }
        float best = a[0] + g[0];
        int bi = 0;
        for (int j = 1; j < MM; ++j) {
            float v = a[j] + g[j];
            if (v > best) { best = v; bi = j; }
        }
        idx = bi;
    }
    const int m = idx;
    if (blockIdx.x == 0 && threadIdx.x == 0) sel[tl] = m;

    const float* src = enc_w + ((size_t)layer * MM + m) * (CC * CC * 9);
    _Float16* dst = W3 + (size_t)tl * 36864;
    for (int i = blockIdx.x * 256 + threadIdx.x; i < 36864; i += gridDim.x * 256) {
        int j   = i & 7;
        int l   = (i >> 3) & 63;
        int o   = (i >> 9) & 1;
        int il  = (i >> 10) & 1;
        int c   = (i >> 11) & 1;
        int tap = i >> 12;                      // 0..8
        int oc  = o * 32 + (l & 31);
        int kch = c * 32 + il * 16 + (l >> 5) * 8 + j;
        dst[i] = (_Float16)src[(oc * CC + kch) * 9 + tap];
    }
}

// ---------------------------------------------------------------------------
// Zero the 1-px borders of chunk-plane padded images.
// ---------------------------------------------------------------------------
__global__ __launch_bounds__(256) void zero_borders(_Float16* __restrict__ base0)
{
    _Float16* base = base0 + (size_t)blockIdx.x * IMGH;
    const int i0 = blockIdx.y * 1032;
    for (int i = i0 + threadIdx.x; i < i0 + 1032; i += 256) {
        // 4128 half8 items: plane(4) x 516 border px x 2
        int pl  = i / 1032;
        int rem = i - pl * 1032;
        int px_idx = rem >> 1, sh = rem & 1;
        int row, col;
        if (px_idx < 130)      { row = 0;            col = px_idx; }
        else if (px_idx < 260) { row = 129;          col = px_idx - 130; }
        else if (px_idx < 388) { row = px_idx - 259; col = 0; }
        else                   { row = px_idx - 387; col = 129; }
        half8 z = {};
        *(half8*)(base + (size_t)pl * CHP + ((size_t)row * PW + col) * 16 + sh * 8) = z;
    }
}

// ---------------------------------------------------------------------------
// x: NCHW fp32 -> chunk-plane padded f16: [B][4][130*130][16] (interior).
// ---------------------------------------------------------------------------
__global__ __launch_bounds__(256) void to_chunked(
    const float* __restrict__ x,    // [B][64][128][128]
    _Float16* __restrict__ act0)
{
    const int xs = blockIdx.x;  // 0..1
    const int y  = blockIdx.y;  // 0..127
    const int b  = blockIdx.z;  // 0..7

    __shared__ _Float16 lds[64 * 72];  // [px][ch], pad 72

    const int wv = threadIdx.x >> 6;
    const int l  = threadIdx.x & 63;
    const float* src = x + ((size_t)b * CC * HH + y) * WW + xs * 64 + l;
#pragma unroll
    for (int k = 0; k < 16; ++k) {
        int ch = wv * 16 + k;
        lds[l * 72 + ch] = (_Float16)src[(size_t)ch * HH * WW];
    }
    __syncthreads();
    int px = threadIdx.x & 63;
    int q  = threadIdx.x >> 6;      // plane
    _Float16* dst = act0 + (size_t)b * IMGH + (size_t)q * CHP
                  + ((size_t)(y + 1) * PW + xs * 64 + px + 1) * 16;
    *(half8*)dst       = *(const half8*)&lds[px * 72 + q * 16];
    *(half8*)(dst + 8) = *(const half8*)&lds[px * 72 + q * 16 + 8];
}

// ---------------------------------------------------------------------------
// 3x3 SAME conv + bias + ReLU, chunk-plane f16 layout, MFMA 32x32x16.
// r5-verified core: 4 phases of 16 ch = one chunk PLANE each (clean line
// consumption), act+weights double-buffered via global_load_lds, phase p+1
// issued before compute(p), __syncthreads (implicit vmcnt0) between.
// decode=1 (last layer): bias+ReLU in-register, 1x1 decoder dot products
// per lane over its 32 channels, __shfl_xor(32) combines ksub halves,
// L2-normalize task 2, write fp32 output directly -- the final activation
// tensor never touches memory and the decoder kernel disappears.
// ---------------------------------------------------------------------------
__global__ __launch_bounds__(256, 2) void conv3x3_mfma(
    const _Float16* __restrict__ in,   // chunked padded, per task stride tsi
    _Float16* __restrict__ out,        // chunked padded, per task stride tso
    const _Float16* __restrict__ W3,   // [12][36864]
    const float* __restrict__ enc_b,   // [L][M][64]
    const int* __restrict__ sel,
    int layer, int task0, size_t tsi, size_t tso,
    const float* __restrict__ dec_w,   // [T][3][64]
    const float* __restrict__ dec_b,   // [T][3]
    float* __restrict__ dout,          // [T][B][3][H][W]
    int decode)
{
    // ---- bijective chunked XCD swizzle over the flattened grid ----
    const int nwg  = gridDim.x * gridDim.y * gridDim.z;   // 768 (fused) / 256
    const int flat = blockIdx.x + gridDim.x * (blockIdx.y + gridDim.y * blockIdx.z);
    const int q8   = nwg >> 3;
    const int logical = (flat & 7) * q8 + (flat >> 3);
    const int bx  = logical & 31;          // gridDim.x == 32
    const int rem = logical >> 5;
    const int b   = rem & 7;               // gridDim.y == 8
    const int tz  = rem >> 3;

    const int y0  = (bx >> 1) * 8;   // padded row of halo top
    const int px0 = (bx & 1) * 64;   // padded col of halo left
    const int t   = task0 + tz;

    const _Float16* inp = in + (size_t)tz * tsi + (size_t)b * IMGH;
    _Float16* outp      = out + (size_t)tz * tso + (size_t)b * IMGH;
    const int tl = t * LL + layer;
    const _Float16* Wt = W3 + (size_t)tl * 36864;

    const int tid  = threadIdx.x;
    const int lane = tid & 63;
    const int w    = tid >> 6;        // wave id; rows 2w, 2w+1 of the 8
    const int n    = lane & 31;
    const int ksub = lane >> 5;

    // act buf: 21 slots x 512 halves = 10752 halves (21504B) each
    // wt buf : 18 frags x 512 halves =  9216 halves (18432B) each
    __shared__ __align__(16) _Float16 lds[2 * 10752 + 2 * 9216];
    _Float16* actb0 = lds;
    _Float16* actb1 = lds + 10752;
    _Float16* wtb0  = lds + 21504;
    _Float16* wtb1  = lds + 21504 + 9216;

    floatx16 acc[2][2][2];   // [rr][o][j]
#pragma unroll
    for (int rr = 0; rr < 2; ++rr)
#pragma unroll
        for (int o = 0; o < 2; ++o)
#pragma unroll
            for (int j = 0; j < 2; ++j)
#pragma unroll
                for (int i = 0; i < 16; ++i) acc[rr][o][j][i] = 0.f;

    // b-frag read offsets (halves) per [dx][h]
    int preoff[3][2];
#pragma unroll
    for (int dx = 0; dx < 3; ++dx)
#pragma unroll
        for (int h = 0; h < 2; ++h) {
            int pxv = dx + n + 32 * h;
            preoff[dx][h] = pxv * 16 + ((ksub ^ ((pxv >> 2) & 1)) << 3);
        }

    // ---- stage one plane-phase (act 21 ops + wt 18 ops) ----
#define STAGE(p, actd, wtd)                                                    \
    {                                                                          \
        const _Float16* plane = inp + (size_t)(p) * CHP;                       \
        for (int j = w; j < 21; j += 4) {                                      \
            int si = j * 64 + lane;          /* 16B slot 0..1343 */            \
            int s16 = si & 1;                                                  \
            int u = si >> 1;                 /* px-slot */                     \
            if (u > 659) u = 659;            /* tail dups -> LDS pad */        \
            int r = (u * 993) >> 16;         /* u/66, exact for u<660 */       \
            int px = u - r * 66;                                               \
            const _Float16* src =                                              \
                plane + ((size_t)(y0 + r) * PW + (px0 + px)) * 16              \
                      + ((s16 ^ ((px >> 2) & 1)) << 3);                        \
            async_ld16(src, (actd) + j * 512);                                 \
        }                                                                      \
        const int c_ = (p) >> 1, il_ = (p) & 1;                                \
        for (int k = w; k < 18; k += 4) {                                      \
            const _Float16* src =                                              \
                Wt + ((k >> 1) * 8 + c_ * 4 + il_ * 2 + (k & 1)) * 512         \
                   + lane * 8;                                                 \
            async_ld16(src, (wtd) + k * 512);                                  \
        }                                                                      \
    }

    // ---- compute one phase from buffers (al, wl) ----
#define COMPUTE(al, wl)                                                        \
    {                                                                          \
        __builtin_amdgcn_s_setprio(1);                                         \
        _Pragma("unroll")                                                      \
        for (int tap = 0; tap < 9; ++tap) {                                    \
            const int dy = tap / 3;                                            \
            const int dx = tap - dy * 3;                                       \
            half8 a0 = *(const half8*)((wl) + (tap * 2 + 0) * 512 + lane * 8); \
            half8 a1 = *(const half8*)((wl) + (tap * 2 + 1) * 512 + lane * 8); \
            _Pragma("unroll")                                                  \
            for (int rr = 0; rr < 2; ++rr) {                                   \
                const _Float16* lb = (al) + (2 * w + rr + dy) * 1056;          \
                half8 b0 = *(const half8*)(lb + preoff[dx][0]);                \
                half8 b1 = *(const half8*)(lb + preoff[dx][1]);                \
                acc[rr][0][0] = __builtin_amdgcn_mfma_f32_32x32x16_f16(a0, b0, acc[rr][0][0], 0, 0, 0); \
                acc[rr][0][1] = __builtin_amdgcn_mfma_f32_32x32x16_f16(a0, b1, acc[rr][0][1], 0, 0, 0); \
                acc[rr][1][0] = __builtin_amdgcn_mfma_f32_32x32x16_f16(a1, b0, acc[rr][1][0], 0, 0, 0); \
                acc[rr][1][1] = __builtin_amdgcn_mfma_f32_32x32x16_f16(a1, b1, acc[rr][1][1], 0, 0, 0); \
            }                                                                  \
        }                                                                      \
        __builtin_amdgcn_s_setprio(0);                                         \
    }

    STAGE(0, actb0, wtb0);
    __syncthreads();                       // phase-0 buffers ready

    STAGE(1, actb1, wtb1);                 // in flight during compute(0)
    __builtin_amdgcn_sched_barrier(0);
    COMPUTE(actb0, wtb0);
    __syncthreads();                       // drains stage(1)

    STAGE(2, actb0, wtb0);
    __builtin_amdgcn_sched_barrier(0);
    COMPUTE(actb1, wtb1);
    __syncthreads();                       // drains stage(2)

    STAGE(3, actb1, wtb1);
    __builtin_amdgcn_sched_barrier(0);
    COMPUTE(actb0, wtb0);
    __syncthreads();                       // drains stage(3)

    COMPUTE(actb1, wtb1);
#undef STAGE
#undef COMPUTE

    // ---- epilogue ----
    int m = sel[t * LL + layer];
    m = __builtin_amdgcn_readfirstlane(m);
    const float* Bp = enc_b + ((size_t)layer * MM + m) * CC;

    if (!decode) {
        // bias + ReLU -> chunk-plane f16 interior
#pragma unroll
        for (int rr = 0; rr < 2; ++rr) {
#pragma unroll
            for (int o = 0; o < 2; ++o)
#pragma unroll
                for (int j = 0; j < 2; ++j) {
                    int px = px0 + j * 32 + n;
                    size_t pxi = (size_t)(y0 + 2 * w + rr + 1) * PW + px + 1;
#pragma unroll
                    for (int rg = 0; rg < 4; ++rg) {
                        int oci = 4 * ksub + 8 * rg;          // 0..28
                        int pl  = o * 2 + (oci >> 4);
                        _Float16* po = outp + (size_t)pl * CHP + pxi * 16 + (oci & 15);
                        half4 h;
#pragma unroll
                        for (int k = 0; k < 4; ++k)
                            h[k] = (_Float16)fmaxf(acc[rr][o][j][rg * 4 + k]
                                                   + Bp[o * 32 + oci + k], 0.f);
                        *(half4*)po = h;
                    }
                }
        }
    } else {
        // fused 1x1 decoder: each lane holds 32 of 64 channels per px.
        const float* dwt = dec_w + (size_t)t * 3 * CC;
        float s[2][2][3];
#pragma unroll
        for (int rr = 0; rr < 2; ++rr)
#pragma unroll
            for (int j = 0; j < 2; ++j)
#pragma unroll
                for (int r3 = 0; r3 < 3; ++r3) s[rr][j][r3] = 0.f;

#pragma unroll
        for (int o = 0; o < 2; ++o)
#pragma unroll
            for (int rg = 0; rg < 4; ++rg)
#pragma unroll
                for (int k = 0; k < 4; ++k) {
                    int ch = o * 32 + 4 * ksub + 8 * rg + k;
                    float bb = Bp[ch];
                    float w0 = dwt[ch];
                    float w1 = dwt[CC + ch];
                    float w2 = dwt[2 * CC + ch];
#pragma unroll
                    for (int rr = 0; rr < 2; ++rr)
#pragma unroll
                        for (int j = 0; j < 2; ++j) {
                            float h = fmaxf(acc[rr][o][j][rg * 4 + k] + bb, 0.f);
                            s[rr][j][0] += h * w0;
                            s[rr][j][1] += h * w1;
                            s[rr][j][2] += h * w2;
                        }
                }

        const int HW = HH * WW;
        float db0 = dec_b[t * 3 + 0];
        float db1 = dec_b[t * 3 + 1];
        float db2 = dec_b[t * 3 + 2];
#pragma unroll
        for (int rr = 0; rr < 2; ++rr)
#pragma unroll
            for (int j = 0; j < 2; ++j) {
                float a0 = s[rr][j][0], a1 = s[rr][j][1], a2 = s[rr][j][2];
                a0 += __shfl_xor(a0, 32, 64);   // combine ksub halves
                a1 += __shfl_xor(a1, 32, 64);
                a2 += __shfl_xor(a2, 32, 64);
                a0 += db0; a1 += db1; a2 += db2;
                if (t == 2) {
                    float r = 1.0f / sqrtf(a0 * a0 + a1 * a1 + a2 * a2);
                    a0 *= r; a1 *= r; a2 *= r;
                }
                if (ksub == 0) {
                    int row = y0 + 2 * w + rr;
                    int col = px0 + j * 32 + n;
                    float* ob = dout + ((size_t)t * BB + b) * 3 * HW
                              + (size_t)row * WW + col;
                    ob[0]      = a0;
                    ob[HW]     = a1;
                    ob[2 * HW] = a2;
                }
            }
    }
}

extern "C" void kernel_launch(void* const* d_in, const int* in_sizes, int n_in,
                              void* d_out, int out_size, void* d_ws, size_t ws_size,
                              hipStream_t stream) {
    const float* x      = (const float*)d_in[0];
    const float* alpha0 = (const float*)d_in[1];
    const float* alphas = (const float*)d_in[2];
    const float* g0     = (const float*)d_in[3];
    const float* gs     = (const float*)d_in[4];
    const float* enc_w  = (const float*)d_in[5];
    const float* enc_b  = (const float*)d_in[6];
    const float* dec_w  = (const float*)d_in[7];
    const float* dec_b  = (const float*)d_in[8];
    float* out = (float*)d_out;

    const size_t ACT = (size_t)BB * IMGH;      // halves per padded activation buffer
    char* pw = (char*)d_ws;
    int* sel = (int*)pw;                 pw += 1024;
    _Float16* W3 = (_Float16*)pw;        pw += (size_t)12 * 36864 * 2;
    _Float16* act0 = (_Float16*)pw;      pw += ACT * 2;
    _Float16* bufs = (_Float16*)pw;
    size_t base = (size_t)(pw - (char*)d_ws);
    bool fused = ws_size >= base + 6 * ACT * 2;

    prep_weights<<<dim3(36, 12), 256, 0, stream>>>(enc_w, alpha0, alphas, g0, gs, sel, W3);
    int nbuf = fused ? 7 : 3;
    zero_borders<<<dim3(nbuf * BB, 4), 256, 0, stream>>>(act0);
    to_chunked<<<dim3(2, HH, BB), 256, 0, stream>>>(x, act0);

    if (fused) {
        _Float16* A = bufs;        // task stride 2*ACT
        _Float16* B = bufs + ACT;  // task stride 2*ACT
        size_t ts = 2 * ACT;
        conv3x3_mfma<<<dim3(32, BB, 3), 256, 0, stream>>>(act0, A, W3, enc_b, sel, 0, 0, 0,  ts,
                                                          dec_w, dec_b, out, 0);
        conv3x3_mfma<<<dim3(32, BB, 3), 256, 0, stream>>>(A,    B, W3, enc_b, sel, 1, 0, ts, ts,
                                                          dec_w, dec_b, out, 0);
        conv3x3_mfma<<<dim3(32, BB, 3), 256, 0, stream>>>(B,    A, W3, enc_b, sel, 2, 0, ts, ts,
                                                          dec_w, dec_b, out, 0);
        // last layer: decoder fused, no activation store
        conv3x3_mfma<<<dim3(32, BB, 3), 256, 0, stream>>>(A,    B, W3, enc_b, sel, 3, 0, ts, ts,
                                                          dec_w, dec_b, out, 1);
    } else {
        _Float16* A = bufs;
        _Float16* B = bufs + ACT;
        for (int t = 0; t < TT; ++t) {
            conv3x3_mfma<<<dim3(32, BB, 1), 256, 0, stream>>>(act0, A, W3, enc_b, sel, 0, t, 0, 0,
                                                              dec_w, dec_b, out, 0);
            conv3x3_mfma<<<dim3(32, BB, 1), 256, 0, stream>>>(A,    B, W3, enc_b, sel, 1, t, 0, 0,
                                                              dec_w, dec_b, out, 0);
            conv3x3_mfma<<<dim3(32, BB, 1), 256, 0, stream>>>(B,    A, W3, enc_b, sel, 2, t, 0, 0,
                                                              dec_w, dec_b, out, 0);
            conv3x3_mfma<<<dim3(32, BB, 1), 256, 0, stream>>>(A,    B, W3, enc_b, sel, 3, t, 0, 0,
                                                              dec_w, dec_b, out, 1);
        }
    }
}

// Round 9
// 228.422 us; speedup vs baseline: 1.1294x; 1.1294x over previous
//
#include <hip/hip_runtime.h>

#define BB 8
#define CC 64
#define HH 128
#define WW 128
#define TT 3
#define LL 4
#define MM 3

#define PW 130                         // padded spatial dim
#define CHP ((size_t)PW * PW * 16)     // halves per 16-ch chunk plane
#define IMGH ((size_t)PW * PW * CC)    // halves per padded image (= 4*CHP)

typedef _Float16 half8 __attribute__((ext_vector_type(8)));
typedef _Float16 half4 __attribute__((ext_vector_type(4)));
typedef float floatx16 __attribute__((ext_vector_type(16)));

__device__ __forceinline__ void async_ld16(const _Float16* g, _Float16* l) {
    __builtin_amdgcn_global_load_lds(
        (const __attribute__((address_space(1))) void*)g,
        (__attribute__((address_space(3))) void*)l, 16, 0, 0);
}

// ---------------------------------------------------------------------------
// Weight prep (+ inline routing): every block recomputes the argmax chain,
// gathers the selected module, fp32 -> fp16, A-frag order:
// W3[tl][tap][c(2)][il(2)][o(2)][lane(64)*8] -- one a-frag = contiguous 1 KB.
// ---------------------------------------------------------------------------
__global__ __launch_bounds__(256) void prep_weights(
    const float* __restrict__ enc_w, // [L][M][64][64][3][3]
    const float* __restrict__ alpha0,
    const float* __restrict__ alphas,
    const float* __restrict__ g0,
    const float* __restrict__ gs,
    int* __restrict__ sel,           // [T][L]
    _Float16* __restrict__ W3)       // [12][36864]
{
    int tl = blockIdx.y;
    int t = tl >> 2, layer = tl & 3;
    int idx = 0;
    for (int l = 0; l <= layer; ++l) {
        const float *a, *g;
        if (l == 0) { a = alpha0 + t * MM; g = g0 + t * MM; }
        else {
            int off = (((l - 1) * TT + t) * MM + idx) * MM;
            a = alphas + off; g = gs + off;
        }
        float best = a[0] + g[0];
        int bi = 0;
        for (int j = 1; j < MM; ++j) {
            float v = a[j] + g[j];
            if (v > best) { best = v; bi = j; }
        }
        idx = bi;
    }
    const int m = idx;
    if (blockIdx.x == 0 && threadIdx.x == 0) sel[tl] = m;

    const float* src = enc_w + ((size_t)layer * MM + m) * (CC * CC * 9);
    _Float16* dst = W3 + (size_t)tl * 36864;
    for (int i = blockIdx.x * 256 + threadIdx.x; i < 36864; i += gridDim.x * 256) {
        int j   = i & 7;
        int l   = (i >> 3) & 63;
        int o   = (i >> 9) & 1;
        int il  = (i >> 10) & 1;
        int c   = (i >> 11) & 1;
        int tap = i >> 12;                      // 0..8
        int oc  = o * 32 + (l & 31);
        int kch = c * 32 + il * 16 + (l >> 5) * 8 + j;
        dst[i] = (_Float16)src[(oc * CC + kch) * 9 + tap];
    }
}

// ---------------------------------------------------------------------------
// Zero the 1-px borders of chunk-plane padded images.
// ---------------------------------------------------------------------------
__global__ __launch_bounds__(256) void zero_borders(_Float16* __restrict__ base0)
{
    _Float16* base = base0 + (size_t)blockIdx.x * IMGH;
    const int i0 = blockIdx.y * 1032;
    for (int i = i0 + threadIdx.x; i < i0 + 1032; i += 256) {
        // 4128 half8 items: plane(4) x 516 border px x 2
        int pl  = i / 1032;
        int rem = i - pl * 1032;
        int px_idx = rem >> 1, sh = rem & 1;
        int row, col;
        if (px_idx < 130)      { row = 0;            col = px_idx; }
        else if (px_idx < 260) { row = 129;          col = px_idx - 130; }
        else if (px_idx < 388) { row = px_idx - 259; col = 0; }
        else                   { row = px_idx - 387; col = 129; }
        half8 z = {};
        *(half8*)(base + (size_t)pl * CHP + ((size_t)row * PW + col) * 16 + sh * 8) = z;
    }
}

// ---------------------------------------------------------------------------
// x: NCHW fp32 -> chunk-plane padded f16: [B][4][130*130][16] (interior).
// ---------------------------------------------------------------------------
__global__ __launch_bounds__(256) void to_chunked(
    const float* __restrict__ x,    // [B][64][128][128]
    _Float16* __restrict__ act0)
{
    const int xs = blockIdx.x;  // 0..1
    const int y  = blockIdx.y;  // 0..127
    const int b  = blockIdx.z;  // 0..7

    __shared__ _Float16 lds[64 * 72];  // [px][ch], pad 72

    const int wv = threadIdx.x >> 6;
    const int l  = threadIdx.x & 63;
    const float* src = x + ((size_t)b * CC * HH + y) * WW + xs * 64 + l;
#pragma unroll
    for (int k = 0; k < 16; ++k) {
        int ch = wv * 16 + k;
        lds[l * 72 + ch] = (_Float16)src[(size_t)ch * HH * WW];
    }
    __syncthreads();
    int px = threadIdx.x & 63;
    int q  = threadIdx.x >> 6;      // plane
    _Float16* dst = act0 + (size_t)b * IMGH + (size_t)q * CHP
                  + ((size_t)(y + 1) * PW + xs * 64 + px + 1) * 16;
    *(half8*)dst       = *(const half8*)&lds[px * 72 + q * 16];
    *(half8*)(dst + 8) = *(const half8*)&lds[px * 72 + q * 16 + 8];
}

// ======================= shared conv macros (r5 core) ======================
#define CONV_PROLOGUE                                                          \
    const int nwg  = gridDim.x * gridDim.y * gridDim.z;                        \
    const int flat = blockIdx.x + gridDim.x * (blockIdx.y + gridDim.y * blockIdx.z); \
    const int q8   = nwg >> 3;                                                 \
    const int logical = (flat & 7) * q8 + (flat >> 3);                         \
    const int bx  = logical & 31;                                              \
    const int rem = logical >> 5;                                              \
    const int b   = rem & 7;                                                   \
    const int tz  = rem >> 3;                                                  \
    const int y0  = (bx >> 1) * 8;                                             \
    const int px0 = (bx & 1) * 64;                                             \
    const int t   = task0 + tz;                                                \
    const _Float16* inp = in + (size_t)tz * tsi + (size_t)b * IMGH;            \
    const int tl = t * LL + layer;                                             \
    const _Float16* Wt = W3 + (size_t)tl * 36864;                              \
    const int tid  = threadIdx.x;                                              \
    const int lane = tid & 63;                                                 \
    const int w    = tid >> 6;                                                 \
    const int n    = lane & 31;                                                \
    const int ksub = lane >> 5;                                                \
    __shared__ __align__(16) _Float16 lds[2 * 10752 + 2 * 9216];               \
    _Float16* actb0 = lds;                                                     \
    _Float16* actb1 = lds + 10752;                                             \
    _Float16* wtb0  = lds + 21504;                                             \
    _Float16* wtb1  = lds + 21504 + 9216;                                      \
    floatx16 acc[2][2][2];                                                     \
    _Pragma("unroll")                                                          \
    for (int rr = 0; rr < 2; ++rr)                                             \
        _Pragma("unroll")                                                      \
        for (int o = 0; o < 2; ++o)                                            \
            _Pragma("unroll")                                                  \
            for (int j = 0; j < 2; ++j)                                        \
                _Pragma("unroll")                                              \
                for (int i = 0; i < 16; ++i) acc[rr][o][j][i] = 0.f;           \
    int preoff[3][2];                                                          \
    _Pragma("unroll")                                                          \
    for (int dx = 0; dx < 3; ++dx)                                             \
        _Pragma("unroll")                                                      \
        for (int h = 0; h < 2; ++h) {                                          \
            int pxv = dx + n + 32 * h;                                         \
            preoff[dx][h] = pxv * 16 + ((ksub ^ ((pxv >> 2) & 1)) << 3);       \
        }

#define STAGE(p, actd, wtd)                                                    \
    {                                                                          \
        const _Float16* plane = inp + (size_t)(p) * CHP;                       \
        for (int j = w; j < 21; j += 4) {                                      \
            int si = j * 64 + lane;          /* 16B slot 0..1343 */            \
            int s16 = si & 1;                                                  \
            int u = si >> 1;                 /* px-slot */                     \
            if (u > 659) u = 659;            /* tail dups -> LDS pad */        \
            int r = (u * 993) >> 16;         /* u/66, exact for u<660 */       \
            int px = u - r * 66;                                               \
            const _Float16* src =                                              \
                plane + ((size_t)(y0 + r) * PW + (px0 + px)) * 16              \
                      + ((s16 ^ ((px >> 2) & 1)) << 3);                        \
            async_ld16(src, (actd) + j * 512);                                 \
        }                                                                      \
        const int c_ = (p) >> 1, il_ = (p) & 1;                                \
        for (int k = w; k < 18; k += 4) {                                      \
            const _Float16* src =                                              \
                Wt + ((k >> 1) * 8 + c_ * 4 + il_ * 2 + (k & 1)) * 512         \
                   + lane * 8;                                                 \
            async_ld16(src, (wtd) + k * 512);                                  \
        }                                                                      \
    }

#define COMPUTE(al, wl)                                                        \
    {                                                                          \
        __builtin_amdgcn_s_setprio(1);                                         \
        _Pragma("unroll")                                                      \
        for (int tap = 0; tap < 9; ++tap) {                                    \
            const int dy = tap / 3;                                            \
            const int dx = tap - dy * 3;                                       \
            half8 a0 = *(const half8*)((wl) + (tap * 2 + 0) * 512 + lane * 8); \
            half8 a1 = *(const half8*)((wl) + (tap * 2 + 1) * 512 + lane * 8); \
            _Pragma("unroll")                                                  \
            for (int rr = 0; rr < 2; ++rr) {                                   \
                const _Float16* lb = (al) + (2 * w + rr + dy) * 1056;          \
                half8 b0 = *(const half8*)(lb + preoff[dx][0]);                \
                half8 b1 = *(const half8*)(lb + preoff[dx][1]);                \
                acc[rr][0][0] = __builtin_amdgcn_mfma_f32_32x32x16_f16(a0, b0, acc[rr][0][0], 0, 0, 0); \
                acc[rr][0][1] = __builtin_amdgcn_mfma_f32_32x32x16_f16(a0, b1, acc[rr][0][1], 0, 0, 0); \
                acc[rr][1][0] = __builtin_amdgcn_mfma_f32_32x32x16_f16(a1, b0, acc[rr][1][0], 0, 0, 0); \
                acc[rr][1][1] = __builtin_amdgcn_mfma_f32_32x32x16_f16(a1, b1, acc[rr][1][1], 0, 0, 0); \
            }                                                                  \
        }                                                                      \
        __builtin_amdgcn_s_setprio(0);                                         \
    }

#define CONV_PIPELINE                                                          \
    STAGE(0, actb0, wtb0);                                                     \
    __syncthreads();                                                           \
    STAGE(1, actb1, wtb1);                                                     \
    __builtin_amdgcn_sched_barrier(0);                                         \
    COMPUTE(actb0, wtb0);                                                      \
    __syncthreads();                                                           \
    STAGE(2, actb0, wtb0);                                                     \
    __builtin_amdgcn_sched_barrier(0);                                         \
    COMPUTE(actb1, wtb1);                                                      \
    __syncthreads();                                                           \
    STAGE(3, actb1, wtb1);                                                     \
    __builtin_amdgcn_sched_barrier(0);                                         \
    COMPUTE(actb0, wtb0);                                                      \
    __syncthreads();                                                           \
    COMPUTE(actb1, wtb1);

// ---------------------------------------------------------------------------
// 3x3 SAME conv + bias + ReLU, chunk-plane f16 layout (layers 0..2).
// Byte-identical structure to the verified r5 kernel (241 us best).
// ---------------------------------------------------------------------------
__global__ __launch_bounds__(256, 2) void conv3x3_mfma(
    const _Float16* __restrict__ in,   // chunked padded, per task stride tsi
    _Float16* __restrict__ out,        // chunked padded, per task stride tso
    const _Float16* __restrict__ W3,   // [12][36864]
    const float* __restrict__ enc_b,   // [L][M][64]
    const int* __restrict__ sel,
    int layer, int task0, size_t tsi, size_t tso)
{
    CONV_PROLOGUE
    _Float16* outp = out + (size_t)tz * tso + (size_t)b * IMGH;

    CONV_PIPELINE

    // ---- epilogue: bias + ReLU -> chunk-plane f16 interior ----
    int m = sel[t * LL + layer];
    m = __builtin_amdgcn_readfirstlane(m);
    const float* Bp = enc_b + ((size_t)layer * MM + m) * CC;
#pragma unroll
    for (int rr = 0; rr < 2; ++rr) {
#pragma unroll
        for (int o = 0; o < 2; ++o)
#pragma unroll
            for (int j = 0; j < 2; ++j) {
                int px = px0 + j * 32 + n;
                size_t pxi = (size_t)(y0 + 2 * w + rr + 1) * PW + px + 1;
#pragma unroll
                for (int rg = 0; rg < 4; ++rg) {
                    int oci = 4 * ksub + 8 * rg;          // 0..28
                    int pl  = o * 2 + (oci >> 4);
                    _Float16* po = outp + (size_t)pl * CHP + pxi * 16 + (oci & 15);
                    half4 h;
#pragma unroll
                    for (int k = 0; k < 4; ++k)
                        h[k] = (_Float16)fmaxf(acc[rr][o][j][rg * 4 + k]
                                               + Bp[o * 32 + oci + k], 0.f);
                    *(half4*)po = h;
                }
            }
    }
}

// ---------------------------------------------------------------------------
// Last layer: same conv core, epilogue = bias+ReLU in-register + fused 1x1
// decoder (+L2-normalize for task 2), fp32 output written directly.  The
// final activation tensor never touches memory.  SEPARATE kernel so the
// decode path's register pressure cannot pollute layers 0..2 (r8 lesson).
// ---------------------------------------------------------------------------
__global__ __launch_bounds__(256, 2) void conv3x3_dec(
    const _Float16* __restrict__ in,   // chunked padded, per task stride tsi
    const _Float16* __restrict__ W3,   // [12][36864]
    const float* __restrict__ enc_b,   // [L][M][64]
    const int* __restrict__ sel,
    int layer, int task0, size_t tsi,
    const float* __restrict__ dec_w,   // [T][3][64]
    const float* __restrict__ dec_b,   // [T][3]
    float* __restrict__ dout)          // [T][B][3][H][W]
{
    CONV_PROLOGUE

    CONV_PIPELINE

    int m = sel[t * LL + layer];
    m = __builtin_amdgcn_readfirstlane(m);
    const float* Bp = enc_b + ((size_t)layer * MM + m) * CC;

    // fused 1x1 decoder: each lane holds 32 of 64 channels per px.
    const float* dwt = dec_w + (size_t)t * 3 * CC;
    float s[2][2][3];
#pragma unroll
    for (int rr = 0; rr < 2; ++rr)
#pragma unroll
        for (int j = 0; j < 2; ++j)
#pragma unroll
            for (int r3 = 0; r3 < 3; ++r3) s[rr][j][r3] = 0.f;

#pragma unroll
    for (int o = 0; o < 2; ++o)
#pragma unroll
        for (int rg = 0; rg < 4; ++rg)
#pragma unroll
            for (int k = 0; k < 4; ++k) {
                int ch = o * 32 + 4 * ksub + 8 * rg + k;
                float bb = Bp[ch];
                float w0 = dwt[ch];
                float w1 = dwt[CC + ch];
                float w2 = dwt[2 * CC + ch];
#pragma unroll
                for (int rr = 0; rr < 2; ++rr)
#pragma unroll
                    for (int j = 0; j < 2; ++j) {
                        float h = fmaxf(acc[rr][o][j][rg * 4 + k] + bb, 0.f);
                        s[rr][j][0] += h * w0;
                        s[rr][j][1] += h * w1;
                        s[rr][j][2] += h * w2;
                    }
            }

    const int HW = HH * WW;
    float db0 = dec_b[t * 3 + 0];
    float db1 = dec_b[t * 3 + 1];
    float db2 = dec_b[t * 3 + 2];
#pragma unroll
    for (int rr = 0; rr < 2; ++rr)
#pragma unroll
        for (int j = 0; j < 2; ++j) {
            float a0 = s[rr][j][0], a1 = s[rr][j][1], a2 = s[rr][j][2];
            a0 += __shfl_xor(a0, 32, 64);   // combine ksub halves
            a1 += __shfl_xor(a1, 32, 64);
            a2 += __shfl_xor(a2, 32, 64);
            a0 += db0; a1 += db1; a2 += db2;
            if (t == 2) {
                float r = 1.0f / sqrtf(a0 * a0 + a1 * a1 + a2 * a2);
                a0 *= r; a1 *= r; a2 *= r;
            }
            if (ksub == 0) {
                int row = y0 + 2 * w + rr;
                int col = px0 + j * 32 + n;
                float* ob = dout + ((size_t)t * BB + b) * 3 * HW
                          + (size_t)row * WW + col;
                ob[0]      = a0;
                ob[HW]     = a1;
                ob[2 * HW] = a2;
            }
        }
}

extern "C" void kernel_launch(void* const* d_in, const int* in_sizes, int n_in,
                              void* d_out, int out_size, void* d_ws, size_t ws_size,
                              hipStream_t stream) {
    const float* x      = (const float*)d_in[0];
    const float* alpha0 = (const float*)d_in[1];
    const float* alphas = (const float*)d_in[2];
    const float* g0     = (const float*)d_in[3];
    const float* gs     = (const float*)d_in[4];
    const float* enc_w  = (const float*)d_in[5];
    const float* enc_b  = (const float*)d_in[6];
    const float* dec_w  = (const float*)d_in[7];
    const float* dec_b  = (const float*)d_in[8];
    float* out = (float*)d_out;

    const size_t ACT = (size_t)BB * IMGH;      // halves per padded activation buffer
    char* pw = (char*)d_ws;
    int* sel = (int*)pw;                 pw += 1024;
    _Float16* W3 = (_Float16*)pw;        pw += (size_t)12 * 36864 * 2;
    _Float16* act0 = (_Float16*)pw;      pw += ACT * 2;
    _Float16* bufs = (_Float16*)pw;
    size_t base = (size_t)(pw - (char*)d_ws);
    bool fused = ws_size >= base + 6 * ACT * 2;

    prep_weights<<<dim3(36, 12), 256, 0, stream>>>(enc_w, alpha0, alphas, g0, gs, sel, W3);
    int nbuf = fused ? 7 : 3;
    zero_borders<<<dim3(nbuf * BB, 4), 256, 0, stream>>>(act0);
    to_chunked<<<dim3(2, HH, BB), 256, 0, stream>>>(x, act0);

    if (fused) {
        _Float16* A = bufs;        // task stride 2*ACT
        _Float16* B = bufs + ACT;  // task stride 2*ACT
        size_t ts = 2 * ACT;
        conv3x3_mfma<<<dim3(32, BB, 3), 256, 0, stream>>>(act0, A, W3, enc_b, sel, 0, 0, 0,  ts);
        conv3x3_mfma<<<dim3(32, BB, 3), 256, 0, stream>>>(A,    B, W3, enc_b, sel, 1, 0, ts, ts);
        conv3x3_mfma<<<dim3(32, BB, 3), 256, 0, stream>>>(B,    A, W3, enc_b, sel, 2, 0, ts, ts);
        // last layer: decoder fused (separate kernel), no activation store
        conv3x3_dec<<<dim3(32, BB, 3), 256, 0, stream>>>(A, W3, enc_b, sel, 3, 0, ts,
                                                         dec_w, dec_b, out);
    } else {
        _Float16* A = bufs;
        _Float16* B = bufs + ACT;
        for (int t = 0; t < TT; ++t) {
            conv3x3_mfma<<<dim3(32, BB, 1), 256, 0, stream>>>(act0, A, W3, enc_b, sel, 0, t, 0, 0);
            conv3x3_mfma<<<dim3(32, BB, 1), 256, 0, stream>>>(A,    B, W3, enc_b, sel, 1, t, 0, 0);
            conv3x3_mfma<<<dim3(32, BB, 1), 256, 0, stream>>>(B,    A, W3, enc_b, sel, 2, t, 0, 0);
            conv3x3_dec<<<dim3(32, BB, 1), 256, 0, stream>>>(A, W3, enc_b, sel, 3, t, 0,
                                                             dec_w, dec_b, out);
        }
    }
}